// Round 1
// baseline (682.447 us; speedup 1.0000x reference)
//
#include <hip/hip_runtime.h>

typedef _Float16 f16;
typedef _Float16 f16x2 __attribute__((ext_vector_type(2)));
typedef _Float16 f16x4 __attribute__((ext_vector_type(4)));
typedef _Float16 f16x8 __attribute__((ext_vector_type(8)));
typedef float    f32x4 __attribute__((ext_vector_type(4)));

#if defined(__has_builtin)
#if __has_builtin(__builtin_amdgcn_fdot2)
#define HAVE_FDOT2 1
#endif
#endif

__device__ __forceinline__ float dot8(f16x8 a, f16x8 b, float acc) {
#ifdef HAVE_FDOT2
  acc = __builtin_amdgcn_fdot2(__builtin_shufflevector(a, a, 0, 1),
                               __builtin_shufflevector(b, b, 0, 1), acc, false);
  acc = __builtin_amdgcn_fdot2(__builtin_shufflevector(a, a, 2, 3),
                               __builtin_shufflevector(b, b, 2, 3), acc, false);
  acc = __builtin_amdgcn_fdot2(__builtin_shufflevector(a, a, 4, 5),
                               __builtin_shufflevector(b, b, 4, 5), acc, false);
  acc = __builtin_amdgcn_fdot2(__builtin_shufflevector(a, a, 6, 7),
                               __builtin_shufflevector(b, b, 6, 7), acc, false);
#else
  #pragma unroll
  for (int i = 0; i < 8; i++) acc += (float)a[i] * (float)b[i];
#endif
  return acc;
}

// ---------------------------------------------------------------------------
// pack x: [B,C,T,F] fp32 -> xi f16 [G][m = b*500+t][i = gf*64+c]
// ---------------------------------------------------------------------------
__global__ void k_pack_x(const float* __restrict__ x, f16* __restrict__ xi) {
  const int tc = blockIdx.x;   // 0..124, 4 timesteps each
  const int b  = blockIdx.y;   // 0..15
  const int t0 = tc * 4;
  const int tid = threadIdx.x; // 256
  __shared__ __align__(16) float lds[64 * 133];  // [c][t*33+f], padded
  #pragma unroll
  for (int it = 0; it < 32; it++) {
    int flat = it * 256 + tid;
    int c = flat >> 7;
    int t = (flat >> 5) & 3;
    int f = flat & 31;
    lds[c * 133 + t * 33 + f] =
        x[(((size_t)b * 64 + c) * 500 + t0 + t) * 32 + f];
  }
  __syncthreads();
  const int w = tid >> 6, l = tid & 63;
  #pragma unroll
  for (int rr = 0; rr < 8; rr++) {
    int row = w * 8 + rr;            // 0..31 = (g,t)
    int g = row >> 2, t = row & 3;
    f16x4 v;
    #pragma unroll
    for (int e = 0; e < 4; e++) {
      int i = l * 4 + e;             // i = gf*64 + c
      int gf = i >> 6, c = i & 63;
      v[e] = (f16)lds[c * 133 + t * 33 + g * 4 + gf];
    }
    *(f16x4*)&xi[((size_t)g * 8000 + (size_t)b * 500 + t0 + t) * 256 + l * 4] = v;
  }
}

// ---------------------------------------------------------------------------
// pack W_ih: fp32 -> f16, same layout [G][768][256]
// ---------------------------------------------------------------------------
__global__ void k_pack_wih(const float* __restrict__ w, f16* __restrict__ wh) {
  size_t i0 = ((size_t)blockIdx.x * 256 + threadIdx.x) * 8;
  f32x4 a = *(const f32x4*)(w + i0);
  f32x4 b = *(const f32x4*)(w + i0 + 4);
  f16x8 v;
  v[0]=(f16)a[0]; v[1]=(f16)a[1]; v[2]=(f16)a[2]; v[3]=(f16)a[3];
  v[4]=(f16)b[0]; v[5]=(f16)b[1]; v[6]=(f16)b[2]; v[7]=(f16)b[3];
  *(f16x8*)(wh + i0) = v;
}

// ---------------------------------------------------------------------------
// pack W_hh into per-thread register layout:
// wp[((g*32+j)*768+tid)*8 + e] = W_hh[g][(tid%192)*4 + (j>>3)][(tid/192)*64 + (j&7)*8 + e]
// ---------------------------------------------------------------------------
__global__ void k_pack_whh(const float* __restrict__ w, f16* __restrict__ wp) {
  const int j = blockIdx.x;    // 0..31
  const int g = blockIdx.y;    // 0..7
  const int tid = threadIdx.x; // 0..767
  const int row = (tid % 192) * 4 + (j >> 3);
  const int kb  = (tid / 192) * 64 + (j & 7) * 8;
  const float* src = w + ((size_t)g * 768 + row) * 256 + kb;
  f16x8 v;
  #pragma unroll
  for (int e = 0; e < 8; e++) v[e] = (f16)src[e];
  *(f16x8*)&wp[(((size_t)g * 32 + j) * 768 + tid) * 8] = v;
}

// ---------------------------------------------------------------------------
// ih GEMM: per g, C[m][o] = sum_i xi[m][i] * Wih[o][i] + bias_ih[o]
// tile M=64 x N=128, BK=64, 4 waves (each 64x32), mfma_f32_16x16x32_f16
// XOR-swizzled LDS (chunk ^= row&7) for conflict-free b128 reads/writes.
// ---------------------------------------------------------------------------
__global__ __launch_bounds__(256) void k_gemm(const f16* __restrict__ xi,
                                              const f16* __restrict__ wih,
                                              const float* __restrict__ bias,
                                              f16* __restrict__ ih) {
  const int mt = blockIdx.x;   // 0..124
  const int nt = blockIdx.y;   // 0..5
  const int g  = blockIdx.z;   // 0..7
  const int tid = threadIdx.x;
  const int w = tid >> 6, l = tid & 63;
  __shared__ __align__(16) f16 Als[64 * 64];
  __shared__ __align__(16) f16 Bls[128 * 64];
  f32x4 zero = {0.f, 0.f, 0.f, 0.f};
  f32x4 acc[4][2];
  #pragma unroll
  for (int mi = 0; mi < 4; mi++)
    #pragma unroll
    for (int ni = 0; ni < 2; ni++) acc[mi][ni] = zero;

  const int arow = tid >> 2, aq = tid & 3;
  const int brow = tid >> 1, bq = tid & 1;
  for (int kk = 0; kk < 4; kk++) {
    const f16* asrc = xi + ((size_t)g * 8000 + mt * 64 + arow) * 256 + kk * 64 + aq * 16;
    f16x8 a0 = *(const f16x8*)asrc;
    f16x8 a1 = *(const f16x8*)(asrc + 8);
    *(f16x8*)&Als[arow * 64 + ((aq * 2 + 0) ^ (arow & 7)) * 8] = a0;
    *(f16x8*)&Als[arow * 64 + ((aq * 2 + 1) ^ (arow & 7)) * 8] = a1;
    const f16* bsrc = wih + ((size_t)g * 768 + nt * 128 + brow) * 256 + kk * 64 + bq * 32;
    #pragma unroll
    for (int jj = 0; jj < 4; jj++) {
      f16x8 v = *(const f16x8*)(bsrc + jj * 8);
      *(f16x8*)&Bls[brow * 64 + ((bq * 4 + jj) ^ (brow & 7)) * 8] = v;
    }
    __syncthreads();
    #pragma unroll
    for (int ks = 0; ks < 2; ks++) {
      f16x8 af[4], bf[2];
      #pragma unroll
      for (int mi = 0; mi < 4; mi++) {
        int r = mi * 16 + (l & 15);
        af[mi] = *(const f16x8*)&Als[r * 64 + ((ks * 4 + (l >> 4)) ^ (r & 7)) * 8];
      }
      #pragma unroll
      for (int ni = 0; ni < 2; ni++) {
        int r = w * 32 + ni * 16 + (l & 15);
        bf[ni] = *(const f16x8*)&Bls[r * 64 + ((ks * 4 + (l >> 4)) ^ (r & 7)) * 8];
      }
      #pragma unroll
      for (int mi = 0; mi < 4; mi++)
        #pragma unroll
        for (int ni = 0; ni < 2; ni++)
          acc[mi][ni] = __builtin_amdgcn_mfma_f32_16x16x32_f16(af[mi], bf[ni], acc[mi][ni], 0, 0, 0);
    }
    __syncthreads();
  }
  #pragma unroll
  for (int ni = 0; ni < 2; ni++) {
    int col = nt * 128 + w * 32 + ni * 16 + (l & 15);
    float bs = bias[g * 768 + col];
    #pragma unroll
    for (int mi = 0; mi < 4; mi++) {
      int m0 = mt * 64 + mi * 16 + (l >> 4) * 4;
      #pragma unroll
      for (int e = 0; e < 4; e++) {
        ih[((size_t)g * 8000 + m0 + e) * 768 + col] = (f16)(acc[mi][ni][e] + bs);
      }
    }
  }
}

// ---------------------------------------------------------------------------
// recurrence: one block per (b,g) chain; W_hh (f16) lives in 128 VGPRs/thread.
// 768 threads: thread owns rows rg*4..rg*4+3 over k-chunk kc*64..+64.
// Per step: partial dots -> LDS reduce -> gates (threads 0..255) -> h f16.
// ---------------------------------------------------------------------------
__global__ __launch_bounds__(768, 3) void k_recur(const f16* __restrict__ ih,
                                                  const f16* __restrict__ wp,
                                                  const float* __restrict__ bias_hh,
                                                  f16* __restrict__ hs,
                                                  float* __restrict__ hlast) {
  const int g = blockIdx.x;    // 0..7
  const int b = blockIdx.y;    // 0..15
  const int tid = threadIdx.x;
  const int kc = tid / 192;    // wave-uniform (3 waves per kc)
  const int rg = tid % 192;
  __shared__ __align__(16) f16 hsm[256];
  __shared__ __align__(16) float partial[4][768];

  f16x8 wv[32];
  {
    const f16x8* src = (const f16x8*)(wp + (size_t)g * 32 * 768 * 8);
    #pragma unroll
    for (int j = 0; j < 32; j++) wv[j] = src[(size_t)j * 768 + tid];
  }
  float bh_r = 0.f, bh_z = 0.f, bh_n = 0.f;
  if (tid < 256) {
    bh_r = bias_hh[g * 768 + tid];
    bh_z = bias_hh[g * 768 + 256 + tid];
    bh_n = bias_hh[g * 768 + 512 + tid];
    hsm[tid] = (f16)0.f;
  }
  const f16* ihb = ih + ((size_t)g * 8000 + (size_t)b * 500) * 768;
  f16* hsp = hs + (size_t)(b * 8 + g) * 500 * 256;
  f16 ri = (f16)0.f, zi = (f16)0.f, nii = (f16)0.f;
  if (tid < 256) { ri = ihb[tid]; zi = ihb[256 + tid]; nii = ihb[512 + tid]; }
  __syncthreads();

  for (int t = 0; t < 500; t++) {
    // prefetch next step's ih (latency hidden under dot phase)
    f16 rin = ri, zin = zi, nin = nii;
    if (tid < 256 && t + 1 < 500) {
      const f16* p = ihb + (size_t)(t + 1) * 768;
      rin = p[tid]; zin = p[256 + tid]; nin = p[512 + tid];
    }
    // phase 1: partial dot products (h broadcast from LDS)
    float a0 = 0.f, a1 = 0.f, a2 = 0.f, a3 = 0.f;
    const f16x8* hv = (const f16x8*)(hsm + kc * 64);
    #pragma unroll
    for (int jj = 0; jj < 8; jj++) {
      f16x8 h8 = hv[jj];
      a0 = dot8(wv[jj],      h8, a0);
      a1 = dot8(wv[8 + jj],  h8, a1);
      a2 = dot8(wv[16 + jj], h8, a2);
      a3 = dot8(wv[24 + jj], h8, a3);
    }
    f32x4 p4; p4[0] = a0; p4[1] = a1; p4[2] = a2; p4[3] = a3;
    *(f32x4*)&partial[kc][rg * 4] = p4;
    __syncthreads();
    // phase 2: reduce + gates on threads 0..255
    if (tid < 256) {
      const int o = tid;
      float rh = partial[0][o] + partial[1][o] + partial[2][o] + partial[3][o] + bh_r;
      float zh = partial[0][256 + o] + partial[1][256 + o] + partial[2][256 + o] + partial[3][256 + o] + bh_z;
      float nh = partial[0][512 + o] + partial[1][512 + o] + partial[2][512 + o] + partial[3][512 + o] + bh_n;
      float r = 1.f / (1.f + __expf(-((float)ri + rh)));
      float z = 1.f / (1.f + __expf(-((float)zi + zh)));
      float nx = (float)nii + r * nh;
      float n = 2.f / (1.f + __expf(-2.f * nx)) - 1.f;
      float hp = (float)hsm[o];
      float hn = (1.f - z) * n + z * hp;
      hsm[o] = (f16)hn;
      hsp[(size_t)t * 256 + o] = (f16)hn;
    }
    __syncthreads();
    ri = rin; zi = zin; nii = nin;
  }
  if (tid < 256) hlast[(size_t)(b * 8 + g) * 256 + tid] = (float)hsm[tid];
}

// ---------------------------------------------------------------------------
// un-transpose: hs f16 [b*8+g][t][o] -> out fp32 [b][och][t][f], f=g*4+gf, o=gf*64+och
// ---------------------------------------------------------------------------
__global__ void k_untr(const f16* __restrict__ hs, float* __restrict__ out) {
  const int tc = blockIdx.x;   // 0..62 (8 t each, tail 4)
  const int b  = blockIdx.y;   // 0..15
  const int t0 = tc * 8;
  const int tid = threadIdx.x; // 256
  __shared__ __align__(16) f16 lds[8 * 8 * 260];  // [(tt*8+g)*260 + o]
  {
    const int row = tid >> 2, q = tid & 3;  // row: 64 = (g,tt)
    const int g = row >> 3, tt = row & 7;
    if (t0 + tt < 500) {
      const f16* src = hs + (((size_t)b * 8 + g) * 500 + t0 + tt) * 256 + q * 64;
      #pragma unroll
      for (int jj = 0; jj < 16; jj++) {
        *(f16x4*)&lds[(tt * 8 + g) * 260 + q * 64 + jj * 4] = *(const f16x4*)(src + jj * 4);
      }
    }
  }
  __syncthreads();
  const int w = tid >> 6, l = tid & 63;
  const int tt2 = w * 2 + (l >> 5);
  const int f = l & 31;
  const int gg = f >> 2, gf = f & 3;
  if (t0 + tt2 < 500) {
    float* dst = out + (((size_t)b * 64) * 500 + t0 + tt2) * 32 + f;
    const f16* srcl = &lds[(tt2 * 8 + gg) * 260 + gf * 64];
    #pragma unroll 4
    for (int och = 0; och < 64; och++) {
      dst[(size_t)och * 500 * 32] = (float)srcl[och];
    }
  }
}

// ---------------------------------------------------------------------------
extern "C" void kernel_launch(void* const* d_in, const int* in_sizes, int n_in,
                              void* d_out, int out_size, void* d_ws, size_t ws_size,
                              hipStream_t stream) {
  const float* x   = (const float*)d_in[0];
  const float* wih = (const float*)d_in[1];
  const float* whh = (const float*)d_in[2];
  const float* bih = (const float*)d_in[3];
  const float* bhh = (const float*)d_in[4];
  float* out   = (float*)d_out;
  float* hlast = out + 16384000;   // B*64*T*F

  char* ws = (char*)d_ws;
  f16* ih_h  = (f16*)(ws);                 //  98,304,000 B : [8][8000][768]
  f16* xi_h  = (f16*)(ws + 98304000);      //  32,768,000 B : [8][8000][256]
  f16* wih_h = (f16*)(ws + 131072000);     //   3,145,728 B : [8][768][256]
  f16* whh_p = (f16*)(ws + 134217728);     //   3,145,728 B : packed
  f16* hs_h  = (f16*)(ws + 137363456);     //  32,768,000 B : [128][500][256]

  k_pack_x  <<<dim3(125, 16), 256, 0, stream>>>(x, xi_h);
  k_pack_wih<<<768, 256, 0, stream>>>(wih, wih_h);
  k_pack_whh<<<dim3(32, 8), 768, 0, stream>>>(whh, whh_p);
  k_gemm    <<<dim3(125, 6, 8), 256, 0, stream>>>(xi_h, wih_h, bih, ih_h);
  k_recur   <<<dim3(8, 16), 768, 0, stream>>>(ih_h, whh_p, bhh, hs_h, hlast);
  k_untr    <<<dim3(63, 16), 256, 0, stream>>>(hs_h, out);
}